// Round 7
// baseline (82.412 us; speedup 1.0000x reference)
//
#include <hip/hip_runtime.h>
#include <stdint.h>
#include <stddef.h>

#define NB 4
#define NC 320
#define NH 128
#define NW 240
#define ND 49
#define HW (NH * NW)             // 30720
#define CC 32                    // channels per chunk
#define NCHUNK (NC / CC)         // 10
#define ROWF 240                 // floats per channel-row
#define ROWS 64                  // rows/chunk: X ch 0..31, Y ch 32..63
#define BUFWORDS (ROWS * ROWF)   // 15360 f32 = 61440 B per buffer
#define CBYTES ((size_t)CC * HW * 4)   // global stride chunk-to-chunk

typedef float f32x4 __attribute__((ext_vector_type(4)));
typedef short s16x8 __attribute__((ext_vector_type(8)));

// HBM -> LDS DMA, 16 B/lane, LDS dest = wave-uniform base + lane*16.
__device__ __forceinline__ void gload_lds16(const void* g, void* l) {
  __builtin_amdgcn_global_load_lds(
      (const __attribute__((address_space(1))) void*)g,
      (__attribute__((address_space(3))) void*)l, 16, 0, 0);
}

// Counted VMEM wait (T4): in-order retirement => vmcnt(16) waits exactly
// for the older chunk while the newer 16 DMAs stay in flight.
template <int N> __device__ __forceinline__ void waitcnt_vm() {
  asm volatile("s_waitcnt vmcnt(%0)" ::"i"(N) : "memory");
  __builtin_amdgcn_sched_barrier(0);   // rule #18
}

// 8 x f32 -> bf16x8 via v_cvt_pk_bf16_f32.
__device__ __forceinline__ s16x8 pack8(const float* f) {
  union { uint32_t u[4]; s16x8 v; } r;
#pragma unroll
  for (int t = 0; t < 4; ++t)
    asm("v_cvt_pk_bf16_f32 %0, %1, %2"
        : "=v"(r.u[t]) : "v"(f[2 * t]), "v"(f[2 * t + 1]));
  return r.v;
}

// One block = one (b,h) row, ALL 15 wi-tiles, full 240-col width.
// Every global read is a 960 B contiguous channel-row (segment-length fix).
// LDS row layout: float offset o within a row holds global w per a rotation
// R(c) = 8*(c>>3) floats, applied on the DMA SOURCE (dest stays linear):
// lane l loads gw = ((l + 2*(c>>3)) % 60)*4 .. +3  ->  LDS o = l*4 .. +3.
// Fragment reads then hit banks m - 8q + const: 2 lanes/bank = free.
__global__ __launch_bounds__(256) void cv_kernel(const float* __restrict__ X,
                                                 const float* __restrict__ Y,
                                                 float* __restrict__ O) {
  __shared__ float lds[2 * BUFWORDS];   // 122880 B -> 1 block/CU
  const int tid = threadIdx.x;
  const int wave = tid >> 6;
  const int l = tid & 63;
  const int m = l & 15;   // fragment row/col
  const int q = l >> 4;   // k-group (8 channels)

  const int bid = blockIdx.x;
  // XCD-chunked bijective swizzle (512 = 8*64).
  const int logical = (bid & 7) * 64 + (bid >> 3);
  const int b = logical >> 7, h = logical & 127;
  const float* xrow = X + (size_t)b * NC * HW + (size_t)h * NW;
  const float* yrow = Y + (size_t)b * NC * HW + (size_t)h * NW;
  float* orow = O + ((size_t)b * NH + h) * NW;

  // ---- DMA setup: instr i = wave*16 + ii covers row i (64 rows/chunk).
  const char* pv[16];
  int loff[16];
#pragma unroll
  for (int ii = 0; ii < 16; ++ii) {
    const int r = wave * 16 + ii;        // 0..31 X, 32..63 Y
    const int cl = r & 31;               // channel within chunk
    int lu = l + 2 * (cl >> 3);          // rotated source lane-unit
    if (lu >= 60) lu -= 60;
    pv[ii] = (const char*)((r < 32 ? xrow : yrow) + (size_t)cl * HW + lu * 4);
    loff[ii] = r * ROWF;
  }

  auto issue = [&](int buf) {            // 16 DMA instrs/wave, 60 lanes each
    if (l < 60) {
#pragma unroll
      for (int ii = 0; ii < 16; ++ii) {
        gload_lds16(pv[ii], lds + buf * BUFWORDS + loff[ii]);
        pv[ii] += CBYTES;
      }
    }
  };

  f32x4 acc[4][4] = {};                  // [tile-slot][ss]

  auto compute = [&](int buf) {
    const float* BX = lds + buf * BUFWORDS;          // X rows 0..31
    const float* BY = BX + 32 * ROWF;                // Y rows 32..63
#pragma unroll
    for (int it = 0; it < 4; ++it) {
      const int wt = wave + it * 4;                  // wi tile 0..14
      if (wt > 14) continue;                         // wave3 it=3 idle
      float fa[8];
      int o4a = 4 * wt + (m >> 2) - 2 * q; if (o4a < 0) o4a += 60;
      const int oa = o4a * 4 + (m & 3);
#pragma unroll
      for (int t = 0; t < 8; ++t) fa[t] = BX[(8 * q + t) * ROWF + oa];
      const s16x8 a = pack8(fa);
#pragma unroll
      for (int ss = 0; ss < 4; ++ss) {
        const int st = wt - 3 + ss;                  // wj tile band
        if (st >= 0) {
          float fb[8];
          int o4b = 4 * st + (m >> 2) - 2 * q; if (o4b < 0) o4b += 60;
          const int ob = o4b * 4 + (m & 3);
#pragma unroll
          for (int t = 0; t < 8; ++t) fb[t] = BY[(8 * q + t) * ROWF + ob];
          const s16x8 bb = pack8(fb);
          acc[it][ss] = __builtin_amdgcn_mfma_f32_16x16x32_bf16(a, bb, acc[it][ss], 0, 0, 0);
        }
      }
    }
  };

  // Pipelined loop (round-6 sync, unchanged): chunk k+1's 16 DMAs stay in
  // flight across compute(k); counted vmcnt never drains the pipe.
  issue(0);
  for (int k = 0; k < NCHUNK; ++k) {
    __builtin_amdgcn_s_barrier();        // compute(k-1) reads all done
    if (k + 1 < NCHUNK) {
      issue((k + 1) & 1);
      waitcnt_vm<16>();                  // chunk k complete, k+1 flying
    } else {
      waitcnt_vm<0>();
    }
    __builtin_amdgcn_s_barrier();        // chunk k visible to all waves
    compute(k & 1);
  }

  // Epilogue: d = wi - wj; virtual tiles (st<0) emit the w<d zeros.
#pragma unroll
  for (int it = 0; it < 4; ++it) {
    const int wt = wave + it * 4;
    if (wt > 14) continue;
#pragma unroll
    for (int ss = 0; ss < 4; ++ss) {
      const int st = wt - 3 + ss;
      const int wj = st * 16 + m;
#pragma unroll
      for (int r = 0; r < 4; ++r) {
        const int wi = wt * 16 + q * 4 + r;   // C/D: row=(lane>>4)*4+reg (m89)
        const int d = wi - wj;
        if (d >= 0 && d < ND) {
          const float v = (st >= 0) ? acc[it][ss][r] : 0.0f;
          orow[(size_t)d * (NB * HW) + wi] = v;
        }
      }
    }
  }
}

extern "C" void kernel_launch(void* const* d_in, const int* in_sizes, int n_in,
                              void* d_out, int out_size, void* d_ws, size_t ws_size,
                              hipStream_t stream) {
  const float* x = (const float*)d_in[0];
  const float* y = (const float*)d_in[1];
  float* out = (float*)d_out;
  cv_kernel<<<dim3(512), dim3(256), 0, stream>>>(x, y, out);
}